// Round 1
// baseline (143.336 us; speedup 1.0000x reference)
//
#include <hip/hip_runtime.h>

#define EPV    0.0001f
#define EPMAXV 30.0f
#define RTOLV  1e-5f
#define ATOLV  1e-8f
#define CHUNK  96

// ---------------------------------------------------------------------------
// ws layout:
//   [0,8)   double acc
//   [8,12)  uint   pair count
//   [16, 16+8*cap)           int2 pairs
//   [16+8*cap, ...)          float pF[(L+cap)*12]   (pred frames: 3x3 rot rows + tran)
//   then                     float tF[(L+cap)*12]   (target frames)
// ---------------------------------------------------------------------------

__global__ void k_pairs(const int* __restrict__ m, int L, int2* __restrict__ pairs,
                        unsigned int* __restrict__ count, int cap) {
    int idx = blockIdx.x * 256 + threadIdx.x;
    if (idx >= L * L) return;
    int i = idx / L, j = idx - i * L;
    if (j > i && m[idx] == 1) {
        unsigned int pos = atomicAdd(count, 1u);
        if (pos < (unsigned int)cap) pairs[pos] = make_int2(i, j);
    }
}

__global__ void k_base(const float* __restrict__ rot, const float* __restrict__ trans,
                       const float* __restrict__ target, int L,
                       float* __restrict__ pF, float* __restrict__ tF) {
    int l = blockIdx.x * 256 + threadIdx.x;
    if (l >= L) return;
    // pred frame = given rot/trans
    float* pf = pF + l * 12;
#pragma unroll
    for (int k = 0; k < 9; k++) pf[k] = rot[l * 9 + k];
    pf[9]  = trans[l * 3 + 0];
    pf[10] = trans[l * 3 + 1];
    pf[11] = trans[l * 3 + 2];
    // target frame = rigid_from_3(target[l])
    const float* tg = target + l * 9;
    float x1x = tg[0], x1y = tg[1], x1z = tg[2];
    float x2x = tg[3], x2y = tg[4], x2z = tg[5];
    float x3x = tg[6], x3y = tg[7], x3z = tg[8];
    float v1x = x3x - x2x, v1y = x3y - x2y, v1z = x3z - x2z;
    float v2x = x1x - x2x, v2y = x1y - x2y, v2z = x1z - x2z;
    float n1 = sqrtf(v1x * v1x + v1y * v1y + v1z * v1z) + 0.001f;
    float e1x = v1x / n1, e1y = v1y / n1, e1z = v1z / n1;
    float c = e1x * v2x + e1y * v2y + e1z * v2z;
    float u2x = v2x - c * e1x, u2y = v2y - c * e1y, u2z = v2z - c * e1z;
    float n2 = sqrtf(u2x * u2x + u2y * u2y + u2z * u2z) + 1e-8f;
    float e2x = u2x / n2, e2y = u2y / n2, e2z = u2z / n2;
    float e3x = e1y * e2z - e1z * e2y;
    float e3y = e1z * e2x - e1x * e2z;
    float e3z = e1x * e2y - e1y * e2x;
    float* tf = tF + l * 12;
    tf[0] = e1x; tf[1] = e1y; tf[2] = e1z;
    tf[3] = e2x; tf[4] = e2y; tf[5] = e2z;
    tf[6] = e3x; tf[7] = e3y; tf[8] = e3z;
    tf[9] = x2x; tf[10] = x2y; tf[11] = x2z;
}

__device__ inline void merge_frames(const float* __restrict__ A, const float* __restrict__ B,
                                    float* __restrict__ out) {
    const float* RA = A; const float* OA = A + 9;
    const float* RB = B; const float* OB = B + 9;
    bool close = (fabsf(OA[0] - OB[0]) <= ATOLV + RTOLV * fabsf(OB[0])) &&
                 (fabsf(OA[1] - OB[1]) <= ATOLV + RTOLV * fabsf(OB[1])) &&
                 (fabsf(OA[2] - OB[2]) <= ATOLV + RTOLV * fabsf(OB[2]));
    float d0 = OB[0] - OA[0], d1 = OB[1] - OA[1], d2 = OB[2] - OA[2];
    float nd = sqrtf(d0 * d0 + d1 * d1 + d2 * d2);
    float nds = (nd == 0.f) ? 1.f : nd;
    float X0 = d0 / nds, X1 = d1 / nds, X2 = d2 / nds;
    float Za0 = RA[6] + RB[6], Za1 = RA[7] + RB[7], Za2 = RA[8] + RB[8];
    float Zs0 = RA[6] - RB[6], Zs1 = RA[7] - RB[7], Zs2 = RA[8] - RB[8];
    float na = sqrtf(Za0 * Za0 + Za1 * Za1 + Za2 * Za2);
    float ns = sqrtf(Zs0 * Zs0 + Zs1 * Zs1 + Zs2 * Zs2);
    float nas = (na == 0.f) ? 1.f : na;
    float nss = (ns == 0.f) ? 1.f : ns;
    float Z0, Z1, Z2;
    if (na > ns) { Z0 = Za0 / nas; Z1 = Za1 / nas; Z2 = Za2 / nas; }
    else         { Z0 = Zs0 / nss; Z1 = Zs1 / nss; Z2 = Zs2 / nss; }
    float Y0 = Z1 * X2 - Z2 * X1;
    float Y1 = Z2 * X0 - Z0 * X2;
    float Y2 = Z0 * X1 - Z1 * X0;
    bool nanbad = (Y0 != Y0) || (Y1 != Y1) || (Y2 != Y2);
    float C0 = X1 * Y2 - X2 * Y1;
    float C1 = X2 * Y0 - X0 * Y2;
    float C2 = X0 * Y1 - X1 * Y0;
    float dotv = C0 * Z0 + C1 * Z1 + C2 * Z2;
    if (dotv < 0.f) { Y0 = -Y0; Y1 = -Y1; Y2 = -Y2; }
    bool bad = close || (nd == 0.f) || (na == 0.f) || (ns == 0.f) || nanbad;
    if (bad) {
#pragma unroll
        for (int k = 0; k < 12; k++) out[k] = A[k];
    } else {
        out[0] = X0; out[1] = X1; out[2] = X2;
        out[3] = Y0; out[4] = Y1; out[5] = Y2;
        out[6] = Z0; out[7] = Z1; out[8] = Z2;
        out[9]  = 0.5f * (OA[0] + OB[0]);
        out[10] = 0.5f * (OA[1] + OB[1]);
        out[11] = 0.5f * (OA[2] + OB[2]);
    }
}

__global__ void k_merge(const int2* __restrict__ pairs, const unsigned int* __restrict__ count,
                        int cap, int L, float* __restrict__ pF, float* __restrict__ tF) {
    int p = blockIdx.x * 256 + threadIdx.x;
    unsigned int cnt = *count;
    if (cnt > (unsigned int)cap) cnt = (unsigned int)cap;
    if (p >= (int)cnt) return;
    int2 ij = pairs[p];
    merge_frames(pF + ij.x * 12, pF + ij.y * 12, pF + (size_t)(L + p) * 12);
    merge_frames(tF + ij.x * 12, tF + ij.y * 12, tF + (size_t)(L + p) * 12);
}

__global__ __launch_bounds__(256)
void k_main(const float* __restrict__ coor, const float* __restrict__ target,
            const float* __restrict__ pF, const float* __restrict__ tF,
            const unsigned int* __restrict__ count, int cap, int L, int Npts,
            double* __restrict__ acc) {
    __shared__ float sC[CHUNK * 3];
    __shared__ float sT[CHUNK * 3];
    __shared__ float sRed[4];
    unsigned int cnt = *count;
    if (cnt > (unsigned int)cap) cnt = (unsigned int)cap;
    int F = L + (int)cnt;
    if ((int)blockIdx.x * 256 >= F) return;   // uniform whole-block exit, before any sync
    int n0 = blockIdx.y * CHUNK;
    int npts = Npts - n0; if (npts > CHUNK) npts = CHUNK;
    for (int idx = threadIdx.x; idx < npts * 3; idx += 256) {
        sC[idx] = coor[n0 * 3 + idx];
        sT[idx] = target[n0 * 3 + idx];
    }
    __syncthreads();
    int f = blockIdx.x * 256 + threadIdx.x;
    bool alive = f < F;
    float P[12], T[12];
    if (alive) {
        const float* pf = pF + (size_t)f * 12;
        const float* tf = tF + (size_t)f * 12;
#pragma unroll
        for (int k = 0; k < 12; k++) { P[k] = pf[k]; T[k] = tf[k]; }
    } else {
#pragma unroll
        for (int k = 0; k < 12; k++) { P[k] = 0.f; T[k] = 0.f; }
    }
    float a = 0.f;
    if (alive) {
#pragma unroll 2
        for (int n = 0; n < npts; n++) {
            float cx = sC[n * 3], cy = sC[n * 3 + 1], cz = sC[n * 3 + 2];
            float dx = cx - P[9], dy = cy - P[10], dz = cz - P[11];
            float ax = P[0] * dx + P[1] * dy + P[2] * dz;
            float ay = P[3] * dx + P[4] * dy + P[5] * dz;
            float az = P[6] * dx + P[7] * dy + P[8] * dz;
            float tx = sT[n * 3], ty = sT[n * 3 + 1], tz = sT[n * 3 + 2];
            float ex = tx - T[9], ey = ty - T[10], ez = tz - T[11];
            float bx = T[0] * ex + T[1] * ey + T[2] * ez;
            float by = T[3] * ex + T[4] * ey + T[5] * ez;
            float bz = T[6] * ex + T[7] * ey + T[8] * ez;
            float qx = ax - bx, qy = ay - by, qz = az - bz;
            float s = qx * qx + qy * qy + qz * qz + 3.0f * EPV;
            float r = sqrtf(s);
            a += fminf(r, EPMAXV);
        }
    }
    // wave (64) shuffle reduce, then cross-wave via LDS
#pragma unroll
    for (int off = 32; off > 0; off >>= 1) a += __shfl_down(a, off, 64);
    int lane = threadIdx.x & 63, wv = threadIdx.x >> 6;
    if (lane == 0) sRed[wv] = a;
    __syncthreads();
    if (threadIdx.x == 0) {
        float s = sRed[0] + sRed[1] + sRed[2] + sRed[3];
        atomicAdd(acc, (double)s);
    }
}

__global__ void k_final(const double* __restrict__ acc, const unsigned int* __restrict__ count,
                        int cap, int L, int Npts, float* __restrict__ out) {
    unsigned int cnt = *count;
    if (cnt > (unsigned int)cap) cnt = (unsigned int)cap;
    double F = (double)(L + (int)cnt);
    out[0] = (float)(*acc / ((double)Npts * F));
}

extern "C" void kernel_launch(void* const* d_in, const int* in_sizes, int n_in,
                              void* d_out, int out_size, void* d_ws, size_t ws_size,
                              hipStream_t stream) {
    const float* coor   = (const float*)d_in[0];
    const float* rot    = (const float*)d_in[1];
    const float* trans  = (const float*)d_in[2];
    const float* target = (const float*)d_in[3];
    const int*   matrix = (const int*)d_in[4];
    int L    = in_sizes[2] / 3;     // trans has L*3 elements
    int Npts = 3 * L;

    char* ws = (char*)d_ws;
    double*       acc   = (double*)ws;
    unsigned int* count = (unsigned int*)(ws + 8);
    // need(cap) = 16 + 8*cap + 96*(L+cap) bytes
    long cap_ws = ((long)ws_size - 16 - 96L * (long)L) / 104;
    long capl = cap_ws < 32768 ? cap_ws : 32768;
    if (capl < 0) capl = 0;
    int cap = (int)(capl & ~1L);    // even -> frames stay 16B-aligned
    int2*  pairs = (int2*)(ws + 16);
    float* pF = (float*)(ws + 16 + (size_t)cap * 8);
    float* tF = pF + (size_t)(L + cap) * 12;

    hipMemsetAsync(ws, 0, 16, stream);
    k_pairs<<<(L * L + 255) / 256, 256, 0, stream>>>(matrix, L, pairs, count, cap);
    k_base<<<(L + 255) / 256, 256, 0, stream>>>(rot, trans, target, L, pF, tF);
    if (cap > 0)
        k_merge<<<(cap + 255) / 256, 256, 0, stream>>>(pairs, count, cap, L, pF, tF);
    int Fmax = L + cap;
    dim3 grid((Fmax + 255) / 256, (Npts + CHUNK - 1) / CHUNK);
    k_main<<<grid, 256, 0, stream>>>(coor, target, pF, tF, count, cap, L, Npts, acc);
    k_final<<<1, 1, 0, stream>>>(acc, count, cap, L, Npts, (float*)d_out);
}